// Round 1
// baseline (144.944 us; speedup 1.0000x reference)
//
#include <hip/hip_runtime.h>

// Problem constants (from reference): x (2,14,128,256,96) f32, wid (2,128,256) int
namespace {
constexpr int kB   = 2;
constexpr int kPl  = 14;
constexpr int kLat = 128;
constexpr int kLon = 256;
constexpr int kC   = 96;
constexpr int kNumDirs = 9;
constexpr int kC4  = kC / 4;                       // 24 float4 per row
constexpr int kNTotal = kB * kPl * kLat * kLon * kC;   // 88,080,384 (fits int)
constexpr int kN4 = kNTotal / 4;                   // 22,020,096 float4
}

// WIND_DIRS lat/lon shifts (scale 2 applied later):
// dir: 0:(0,0) 1:(-1,0) 2:(-1,1) 3:(0,1) 4:(1,1) 5:(1,0) 6:(1,-1) 7:(0,-1) 8:(-1,-1)
__device__ __constant__ int c_lat_s[kNumDirs] = {0,-1,-1, 0, 1, 1, 1, 0,-1};
__device__ __constant__ int c_lon_s[kNumDirs] = {0, 0, 1, 1, 1, 0,-1,-1,-1};

__global__ void zero_counts_kernel(int* __restrict__ gcounts) {
    if (threadIdx.x < kNumDirs) gcounts[threadIdx.x] = 0;
}

// One block per (b, rlat, rlon) region of 32x32. Computes:
//  - packed shift deltas for the region's dominant dir -> rdpack[blk]
//  - contributes to global 9-bin histogram -> gcounts
__global__ __launch_bounds__(256) void region_dirs_kernel(
        const int* __restrict__ wid, int* __restrict__ rdpack,
        int* __restrict__ gcounts) {
    __shared__ int cnt[kNumDirs];
    const int t = threadIdx.x;
    if (t < kNumDirs) cnt[t] = 0;
    __syncthreads();

    const int blk  = blockIdx.x;        // 0..63
    const int rlon = blk & 7;
    const int rlat = (blk >> 3) & 3;
    const int b    = blk >> 5;

    // 32x32 = 1024 elements, 256 threads -> 4 each
    for (int k = t; k < 1024; k += 256) {
        const int i  = k >> 5;
        const int j  = k & 31;
        const int la = rlat * 32 + i;
        const int lo = rlon * 32 + j;
        const int d  = wid[(b * kLat + la) * kLon + lo];
        atomicAdd(&cnt[d], 1);
    }
    __syncthreads();

    if (t == 0) {
        int best = 0, bestc = cnt[0];
        #pragma unroll
        for (int d = 1; d < kNumDirs; ++d) {
            if (cnt[d] > bestc) { bestc = cnt[d]; best = d; }  // first-max tie-break
        }
        // combined source offsets: la_src = (la + 3 - 2*lat_s) & 127, lo_src = (lo + 6 - 2*lon_s) & 255
        const int dla = 3 - 2 * c_lat_s[best];   // in {1,3,5}
        const int dlo = 6 - 2 * c_lon_s[best];   // in {4,6,8}
        rdpack[blk] = (dla << 8) | dlo;
    }
    if (t < kNumDirs) atomicAdd(&gcounts[t], cnt[t]);
}

__global__ void finalize_kernel(const int* __restrict__ gcounts,
                                float* __restrict__ out_dom) {
    int best = 0, bestc = gcounts[0];
    #pragma unroll
    for (int d = 1; d < kNumDirs; ++d) {
        if (gcounts[d] > bestc) { bestc = gcounts[d]; best = d; }
    }
    *out_dom = (float)best;
}

// Pure gather: out[b,p,la,lo,c] = x[b,(p+1)%14,(la+dla)&127,(lo+dlo)&255,c]
__global__ __launch_bounds__(256) void gather_kernel(
        const float4* __restrict__ x, const int* __restrict__ rdpack,
        float4* __restrict__ out) {
    const int stride = gridDim.x * blockDim.x;
    for (int i = blockIdx.x * blockDim.x + threadIdx.x; i < kN4; i += stride) {
        const int c4 = i % kC4;
        int r = i / kC4;
        const int lo = r & (kLon - 1); r >>= 8;
        const int la = r & (kLat - 1); r >>= 7;
        const int p  = r % kPl;
        const int b  = r / kPl;

        const int pack = rdpack[(b * 4 + (la >> 5)) * 8 + (lo >> 5)];
        const int lasrc = (la + (pack >> 8)) & (kLat - 1);
        const int losrc = (lo + (pack & 0xff)) & (kLon - 1);
        int psrc = p + 1; if (psrc >= kPl) psrc = 0;

        const int src = (((b * kPl + psrc) * kLat + lasrc) * kLon + losrc) * kC4 + c4;
        out[i] = x[src];
    }
}

extern "C" void kernel_launch(void* const* d_in, const int* in_sizes, int n_in,
                              void* d_out, int out_size, void* d_ws, size_t ws_size,
                              hipStream_t stream) {
    const float* x   = (const float*)d_in[0];
    const int*   wid = (const int*)d_in[1];
    float* out = (float*)d_out;

    // ws layout: [0..8] global counts, [16..79] packed region deltas
    int* gcounts = (int*)d_ws;
    int* rdpack  = gcounts + 16;

    zero_counts_kernel<<<1, 64, 0, stream>>>(gcounts);
    region_dirs_kernel<<<kB * 4 * 8, 256, 0, stream>>>(wid, rdpack, gcounts);
    finalize_kernel<<<1, 1, 0, stream>>>(gcounts, out + kNTotal);

    const int blocks = 4096;
    gather_kernel<<<blocks, 256, 0, stream>>>((const float4*)x, rdpack,
                                              (float4*)out);
}

// Round 3
// 140.852 us; speedup vs baseline: 1.0291x; 1.0291x over previous
//
#include <hip/hip_runtime.h>

// Problem constants (from reference): x (2,14,128,256,96) f32, wid (2,128,256) int
namespace {
constexpr int kB   = 2;
constexpr int kPl  = 14;
constexpr int kLat = 128;
constexpr int kLon = 256;
constexpr int kC   = 96;
constexpr int kNumDirs = 9;
constexpr int kC4  = kC / 4;                         // 24 float4 per row
constexpr int kNTotal = kB * kPl * kLat * kLon * kC; // 88,080,384
constexpr int kN4 = kNTotal / 4;                     // 22,020,096 = 2^20 * 21
constexpr int kRegions = kB * 4 * 8;                 // 64
constexpr int kCopyBlocks = 1024;                    // 2^18 threads -> 84 f4/thread
constexpr int kItersPerThread = kN4 / (kCopyBlocks * 256); // 84
}

typedef float f4 __attribute__((ext_vector_type(4)));  // native vec for nontemporal builtins

// WIND_DIRS lat/lon shifts (scale 2 applied in packing):
// dir: 0:(0,0) 1:(-1,0) 2:(-1,1) 3:(0,1) 4:(1,1) 5:(1,0) 6:(1,-1) 7:(0,-1) 8:(-1,-1)
__device__ __constant__ int c_lat_s[kNumDirs] = {0,-1,-1, 0, 1, 1, 1, 0,-1};
__device__ __constant__ int c_lon_s[kNumDirs] = {0, 0, 1, 1, 1, 0,-1,-1,-1};

// One block per (b, rlat, rlon) 32x32 region:
//  - rdpack[blk] = packed (dla<<8 | dlo) source-offset for the dominant dir
//  - cnt_blk[blk][9] = this region's histogram (plain stores; summed later)
__global__ __launch_bounds__(256) void region_dirs_kernel(
        const int* __restrict__ wid, int* __restrict__ rdpack,
        int* __restrict__ cnt_blk) {
    __shared__ int cnt[kNumDirs];
    const int t = threadIdx.x;
    if (t < kNumDirs) cnt[t] = 0;
    __syncthreads();

    const int blk  = blockIdx.x;        // 0..63
    const int rlon = blk & 7;
    const int rlat = (blk >> 3) & 3;
    const int b    = blk >> 5;

    for (int k = t; k < 1024; k += 256) {
        const int i  = k >> 5;
        const int j  = k & 31;
        const int la = rlat * 32 + i;
        const int lo = rlon * 32 + j;
        atomicAdd(&cnt[wid[(b * kLat + la) * kLon + lo]], 1);
    }
    __syncthreads();

    if (t < kNumDirs) cnt_blk[blk * kNumDirs + t] = cnt[t];
    if (t == 0) {
        int best = 0, bestc = cnt[0];
        #pragma unroll
        for (int d = 1; d < kNumDirs; ++d)
            if (cnt[d] > bestc) { bestc = cnt[d]; best = d; }  // first-max tie
        const int dla = 3 - 2 * c_lat_s[best];   // {1,3,5}
        const int dlo = 6 - 2 * c_lon_s[best];   // {4,6,8}
        rdpack[blk] = (dla << 8) | dlo;
    }
}

// Pure gather permutation: out[b,p,la,lo,c] = x[b,(p+1)%14,(la+dla)&127,(lo+dlo)&255,c]
// Blocks 0..kCopyBlocks-1 copy; block kCopyBlocks reduces the global histogram.
__global__ __launch_bounds__(256) void gather_kernel(
        const f4* __restrict__ x, const int* __restrict__ rdpack,
        const int* __restrict__ cnt_blk, f4* __restrict__ out,
        float* __restrict__ out_dom) {
    if (blockIdx.x == kCopyBlocks) {
        // global dominant direction: sum 64 region histograms, first-max argmax
        __shared__ int tot[kNumDirs];
        const int t = threadIdx.x;
        if (t < kNumDirs) {
            int s = 0;
            for (int r = 0; r < kRegions; ++r) s += cnt_blk[r * kNumDirs + t];
            tot[t] = s;
        }
        __syncthreads();
        if (t == 0) {
            int best = 0, bestc = tot[0];
            #pragma unroll
            for (int d = 1; d < kNumDirs; ++d)
                if (tot[d] > bestc) { bestc = tot[d]; best = d; }
            *out_dom = (float)best;
        }
        return;
    }

    const int base = blockIdx.x * 256 + threadIdx.x;   // 0 .. 2^18-1
    constexpr int kStride = kCopyBlocks * 256;         // 2^18

    #pragma unroll 4
    for (int k = 0; k < kItersPerThread; ++k) {
        const int i = base + k * kStride;
        const int c4 = i % kC4;
        int r = i / kC4;
        const int lo = r & (kLon - 1); r >>= 8;
        const int la = r & (kLat - 1); r >>= 7;
        const int p  = r % kPl;
        const int b  = r / kPl;

        const int pack = rdpack[(b * 4 + (la >> 5)) * 8 + (lo >> 5)];
        const int lasrc = (la + (pack >> 8)) & (kLat - 1);
        const int losrc = (lo + (pack & 0xff)) & (kLon - 1);
        int psrc = p + 1; if (psrc >= kPl) psrc = 0;

        const int src = (((b * kPl + psrc) * kLat + lasrc) * kLon + losrc) * kC4 + c4;
        const f4 v = __builtin_nontemporal_load(&x[src]);
        __builtin_nontemporal_store(v, &out[i]);
    }
}

extern "C" void kernel_launch(void* const* d_in, const int* in_sizes, int n_in,
                              void* d_out, int out_size, void* d_ws, size_t ws_size,
                              hipStream_t stream) {
    const float* x   = (const float*)d_in[0];
    const int*   wid = (const int*)d_in[1];
    float* out = (float*)d_out;

    // ws layout: [0..63] rdpack, [64..64+576) per-block counts
    int* rdpack  = (int*)d_ws;
    int* cnt_blk = rdpack + kRegions;

    region_dirs_kernel<<<kRegions, 256, 0, stream>>>(wid, rdpack, cnt_blk);
    gather_kernel<<<kCopyBlocks + 1, 256, 0, stream>>>(
        (const f4*)x, rdpack, cnt_blk, (f4*)out, out + kNTotal);
}